// Round 7
// baseline (124.678 us; speedup 1.0000x reference)
//
#include <hip/hip_runtime.h>
#include <math.h>

#define NEXP 64
#define TOPK 8
#define TILE 128          // tokens per tile; 2 waves per block, wave-local halves
#define PITCH 65          // float pitch: scalar LDS ops -> perfect 2-way banks (free)
#define MAXGRID 1024

typedef float v4 __attribute__((ext_vector_type(4)));

__device__ __forceinline__ void load_wave(v4* __restrict__ buf,
                                          const float* __restrict__ logits,
                                          long tokBase, int w, int l)
{
    const v4* g = (const v4*)logits + tokBase * (NEXP / 4) + (w << 10);
    #pragma unroll
    for (int k = 0; k < 16; ++k)
        buf[k] = __builtin_nontemporal_load(&g[l + (k << 6)]);
}

__device__ __forceinline__ void stage_tile(const v4* __restrict__ buf,
                                           float* __restrict__ out_logits,
                                           float* __restrict__ tile,
                                           long tokBase, int w, int l)
{
    v4* gpass = (v4*)out_logits + tokBase * (NEXP / 4);
    #pragma unroll
    for (int k = 0; k < 16; ++k) {
        int i = (w << 10) + l + (k << 6);     // wave-local flat v4 index
        v4 v = buf[k];
        __builtin_nontemporal_store(v, &gpass[i]);
        int r  = i >> 4;                      // token row
        int c4 = (i & 15) << 2;
        float* b = &tile[r * PITCH + c4];
        b[0] = v.x; b[1] = v.y; b[2] = v.z; b[3] = v.w;
    }
}

__device__ __forceinline__ void compute_tile(const float* __restrict__ tile,
                                             const v4* __restrict__ buf,
                                             float* __restrict__ out_rw,
                                             float* __restrict__ out_tw,
                                             float* __restrict__ out_ti,
                                             long tokBase, int w, int l, int tid)
{
    // ---- per-token sweep: top-8 insert (strict >, lowest-index ties) + sum(exp)
    const float* __restrict__ row = &tile[tid * PITCH];
    float vals[TOPK], ids[TOPK];
    #pragma unroll
    for (int j = 0; j < TOPK; ++j) { vals[j] = -INFINITY; ids[j] = 0.0f; }
    float ssum = 0.0f;

    #pragma unroll 8
    for (int e = 0; e < NEXP; ++e) {
        float x = row[e];
        ssum += __expf(x);
        float fe = (float)e;
        bool c[TOPK];
        #pragma unroll
        for (int j = 0; j < TOPK; ++j) c[j] = x > vals[j];
        #pragma unroll
        for (int j = TOPK - 1; j >= 1; --j) {
            ids[j]  = c[j] ? (c[j - 1] ? ids[j - 1] : fe) : ids[j];
            vals[j] = __builtin_amdgcn_fmed3f(x, vals[j - 1], vals[j]);
        }
        ids[0]  = c[0] ? fe : ids[0];
        vals[0] = fmaxf(vals[0], x);
    }
    const float sinv = 1.0f / ssum;

    // ---- top-k weights from registers (softmax denominator cancels)
    float ew[TOPK];
    float tsum = 0.0f;
    #pragma unroll
    for (int j = 0; j < TOPK; ++j) { ew[j] = __expf(vals[j]); tsum += ew[j]; }
    const float tinv = 1.0f / tsum;

    const long tok = tokBase + tid;
    v4* twp = (v4*)out_tw + tok * 2;
    v4* tip = (v4*)out_ti + tok * 2;
    v4 w0 = { ew[0] * tinv, ew[1] * tinv, ew[2] * tinv, ew[3] * tinv };
    v4 w1 = { ew[4] * tinv, ew[5] * tinv, ew[6] * tinv, ew[7] * tinv };
    v4 i0 = { ids[0], ids[1], ids[2], ids[3] };
    v4 i1 = { ids[4], ids[5], ids[6], ids[7] };
    __builtin_nontemporal_store(w0, &twp[0]);
    __builtin_nontemporal_store(w1, &twp[1]);
    __builtin_nontemporal_store(i0, &tip[0]);
    __builtin_nontemporal_store(i1, &tip[1]);

    // ---- rw from the surviving prefetch registers: exp(x) * shfl(sinv)
    v4* grw = (v4*)out_rw + tokBase * (NEXP / 4);
    #pragma unroll
    for (int k = 0; k < 16; ++k) {
        int i = (w << 10) + l + (k << 6);
        float si = __shfl(sinv, (l >> 4) + 4 * k);   // wave-local source lane
        v4 x = buf[k];
        v4 o;
        o.x = __expf(x.x) * si;
        o.y = __expf(x.y) * si;
        o.z = __expf(x.z) * si;
        o.w = __expf(x.w) * si;
        __builtin_nontemporal_store(o, &grw[i]);
    }
}

// Main kernel: ZERO barriers, ZERO atomics. Wave-private LDS halves.
__global__ __launch_bounds__(TILE) void router_kernel(
    const float* __restrict__ logits,
    float* __restrict__ out_logits,
    float* __restrict__ out_rw,
    float* __restrict__ out_tw,
    float* __restrict__ out_ti,
    int nTiles)
{
    __shared__ float tile[TILE * PITCH];
    const int tid = threadIdx.x;
    const int w   = tid >> 6;
    const int l   = tid & 63;
    const int stride = gridDim.x;

    v4 bufA[16], bufB[16];
    int tb = blockIdx.x;
    load_wave(bufA, logits, (long)tb * TILE, w, l);

    for (; tb < nTiles; tb += 2 * stride) {
        const long baseA = (long)tb * TILE;
        stage_tile(bufA, out_logits, tile, baseA, w, l);
        const int t1 = tb + stride;
        if (t1 < nTiles) load_wave(bufB, logits, (long)t1 * TILE, w, l);
        compute_tile(tile, bufA, out_rw, out_tw, out_ti, baseA, w, l, tid);

        if (t1 < nTiles) {
            const long baseB = (long)t1 * TILE;
            stage_tile(bufB, out_logits, tile, baseB, w, l);
            const int t2 = tb + 2 * stride;
            if (t2 < nTiles) load_wave(bufA, logits, (long)t2 * TILE, w, l);
            compute_tile(tile, bufB, out_rw, out_tw, out_ti, baseB, w, l, tid);
        }
    }
}

// Histogram kernel: re-reads topk_ids (L3-hot), per-block LDS hist,
// one 64-lane flush per block -> 16K global RMWs spread over the kernel.
__global__ __launch_bounds__(256) void hist_kernel(
    const float* __restrict__ ti, float* __restrict__ out_hist, int n4)
{
    __shared__ float shist[NEXP];
    const int tid = threadIdx.x;
    if (tid < NEXP) shist[tid] = 0.0f;
    __syncthreads();

    const v4* t4 = (const v4*)ti;
    const int step = gridDim.x * 256;
    for (int i = blockIdx.x * 256 + tid; i < n4; i += step) {
        v4 v = t4[i];
        atomicAdd(&shist[(int)v.x], 1.0f);
        atomicAdd(&shist[(int)v.y], 1.0f);
        atomicAdd(&shist[(int)v.z], 1.0f);
        atomicAdd(&shist[(int)v.w], 1.0f);
    }
    __syncthreads();
    if (tid < NEXP) atomicAdd(&out_hist[tid], shist[tid]);
}

extern "C" void kernel_launch(void* const* d_in, const int* in_sizes, int n_in,
                              void* d_out, int out_size, void* d_ws, size_t ws_size,
                              hipStream_t stream) {
    const float* logits = (const float*)d_in[0];
    const long T = (long)in_sizes[0] / NEXP;

    float* out      = (float*)d_out;
    float* o_logits = out;
    float* o_rw     = out + T * NEXP;
    float* o_tw     = out + 2 * T * NEXP;
    float* o_ti     = o_tw + T * TOPK;
    float* o_hist   = o_ti + T * TOPK;

    (void)hipMemsetAsync(o_hist, 0, NEXP * sizeof(float), stream);

    const int nTiles = (int)(T / TILE);        // 4096
    const int grid   = nTiles < MAXGRID ? nTiles : MAXGRID;
    router_kernel<<<grid, TILE, 0, stream>>>(logits, o_logits, o_rw, o_tw, o_ti,
                                             nTiles);

    const int n4 = (int)(T * TOPK / 4);        // 1,048,576 v4 of ids
    hist_kernel<<<256, 256, 0, stream>>>(o_ti, o_hist, n4);
}

// Round 8
// 107.054 us; speedup vs baseline: 1.1646x; 1.1646x over previous
//
#include <hip/hip_runtime.h>
#include <math.h>

#define NEXP 64
#define TOPK 8
#define TILE 128          // tokens per tile; 2 waves per block, wave-local halves
#define PITCH 65          // float pitch: scalar LDS ops -> perfect 2-way banks (free)

typedef float v4 __attribute__((ext_vector_type(4)));

__device__ __forceinline__ void load_wave(v4* __restrict__ buf,
                                          const float* __restrict__ logits,
                                          long tokBase, int w, int l)
{
    const v4* g = (const v4*)logits + tokBase * (NEXP / 4) + (w << 10);
    #pragma unroll
    for (int k = 0; k < 16; ++k)
        buf[k] = __builtin_nontemporal_load(&g[l + (k << 6)]);   // read-once: keep NT
}

__device__ __forceinline__ void stage_tile(const v4* __restrict__ buf,
                                           float* __restrict__ out_logits,
                                           float* __restrict__ tile,
                                           long tokBase, int w, int l)
{
    v4* gpass = (v4*)out_logits + tokBase * (NEXP / 4);
    #pragma unroll
    for (int k = 0; k < 16; ++k) {
        int i = (w << 10) + l + (k << 6);     // wave-local flat v4 index
        v4 v = buf[k];
        gpass[i] = v;                          // PLAIN store (L2 write-allocate)
        int r  = i >> 4;                       // token row
        int c4 = (i & 15) << 2;
        float* b = &tile[r * PITCH + c4];
        b[0] = v.x; b[1] = v.y; b[2] = v.z; b[3] = v.w;
    }
}

__device__ __forceinline__ void compute_tile(const float* __restrict__ tile,
                                             const v4* __restrict__ buf,
                                             float* __restrict__ out_rw,
                                             float* __restrict__ out_tw,
                                             float* __restrict__ out_ti,
                                             float* shist,
                                             long tokBase, int w, int l, int tid)
{
    // ---- per-token sweep: top-8 insert (strict >, lowest-index ties) + sum(exp)
    const float* __restrict__ row = &tile[tid * PITCH];
    float vals[TOPK], ids[TOPK];
    #pragma unroll
    for (int j = 0; j < TOPK; ++j) { vals[j] = -INFINITY; ids[j] = 0.0f; }
    float ssum = 0.0f;

    #pragma unroll 8
    for (int e = 0; e < NEXP; ++e) {
        float x = row[e];
        ssum += __expf(x);
        float fe = (float)e;
        bool c[TOPK];
        #pragma unroll
        for (int j = 0; j < TOPK; ++j) c[j] = x > vals[j];
        #pragma unroll
        for (int j = TOPK - 1; j >= 1; --j) {
            ids[j]  = c[j] ? (c[j - 1] ? ids[j - 1] : fe) : ids[j];
            vals[j] = __builtin_amdgcn_fmed3f(x, vals[j - 1], vals[j]);
        }
        ids[0]  = c[0] ? fe : ids[0];
        vals[0] = fmaxf(vals[0], x);
    }
    const float sinv = 1.0f / ssum;

    // ---- top-k weights from registers (softmax denominator cancels)
    float ew[TOPK];
    float tsum = 0.0f;
    #pragma unroll
    for (int j = 0; j < TOPK; ++j) { ew[j] = __expf(vals[j]); tsum += ew[j]; }
    const float tinv = 1.0f / tsum;

    const long tok = tokBase + tid;
    v4* twp = (v4*)out_tw + tok * 2;
    v4* tip = (v4*)out_ti + tok * 2;
    v4 w0 = { ew[0] * tinv, ew[1] * tinv, ew[2] * tinv, ew[3] * tinv };
    v4 w1 = { ew[4] * tinv, ew[5] * tinv, ew[6] * tinv, ew[7] * tinv };
    v4 i0 = { ids[0], ids[1], ids[2], ids[3] };
    v4 i1 = { ids[4], ids[5], ids[6], ids[7] };
    twp[0] = w0;                               // PLAIN stores
    twp[1] = w1;
    tip[0] = i0;
    tip[1] = i1;

    // ---- histogram into block-local LDS (proven ~free in-kernel, R6 vs R7)
    #pragma unroll
    for (int j = 0; j < TOPK; ++j)
        atomicAdd(&shist[(int)ids[j]], 1.0f);

    // ---- rw from the surviving prefetch registers: exp(x) * shfl(sinv)
    v4* grw = (v4*)out_rw + tokBase * (NEXP / 4);
    #pragma unroll
    for (int k = 0; k < 16; ++k) {
        int i = (w << 10) + l + (k << 6);
        float si = __shfl(sinv, (l >> 4) + 4 * k);   // wave-local source lane
        v4 x = buf[k];
        v4 o;
        o.x = __expf(x.x) * si;
        o.y = __expf(x.y) * si;
        o.z = __expf(x.z) * si;
        o.w = __expf(x.w) * si;
        grw[i] = o;                            // PLAIN store
    }
}

__global__ __launch_bounds__(TILE) void router_kernel(
    const float* __restrict__ logits,
    float* __restrict__ out_logits,
    float* __restrict__ out_rw,
    float* __restrict__ out_tw,
    float* __restrict__ out_ti,
    float* __restrict__ out_hist,
    int nTiles)
{
    __shared__ float tile[TILE * PITCH];   // wave-private halves; no in-loop barriers
    __shared__ float shist[NEXP];

    const int tid = threadIdx.x;
    const int w   = tid >> 6;
    const int l   = tid & 63;
    if (tid < NEXP) shist[tid] = 0.0f;
    __syncthreads();                       // one-time: shist visible to both waves

    const int grid = gridDim.x;
    const int tA = blockIdx.x;             // first tile
    const int tB = tA + grid;              // second tile (if present)
    const long baseA = (long)tA * TILE;
    const long baseB = (long)tB * TILE;
    const bool hasB = tB < nTiles;

    v4 bufA[16], bufB[16];

    load_wave(bufA, logits, baseA, w, l);
    stage_tile(bufA, out_logits, tile, baseA, w, l);
    if (hasB) load_wave(bufB, logits, baseB, w, l);   // in flight under compute A
    compute_tile(tile, bufA, out_rw, out_tw, out_ti, shist, baseA, w, l, tid);

    if (hasB) {
        stage_tile(bufB, out_logits, tile, baseB, w, l);
        compute_tile(tile, bufB, out_rw, out_tw, out_ti, shist, baseB, w, l, tid);
    }

    // ---- flush histogram: one 64-lane global atomic per block ----
    __syncthreads();
    if (tid < NEXP) atomicAdd(&out_hist[tid], shist[tid]);
}

extern "C" void kernel_launch(void* const* d_in, const int* in_sizes, int n_in,
                              void* d_out, int out_size, void* d_ws, size_t ws_size,
                              hipStream_t stream) {
    const float* logits = (const float*)d_in[0];
    const long T = (long)in_sizes[0] / NEXP;

    float* out      = (float*)d_out;
    float* o_logits = out;
    float* o_rw     = out + T * NEXP;
    float* o_tw     = out + 2 * T * NEXP;
    float* o_ti     = o_tw + T * TOPK;
    float* o_hist   = o_ti + T * TOPK;

    (void)hipMemsetAsync(o_hist, 0, NEXP * sizeof(float), stream);

    const int nTiles = (int)(T / TILE);        // 4096
    const int grid   = (nTiles + 1) / 2;       // 2048: each block does 2 tiles
    router_kernel<<<grid, TILE, 0, stream>>>(logits, o_logits, o_rw, o_tw, o_ti,
                                             o_hist, nTiles);
}

// Round 9
// 104.580 us; speedup vs baseline: 1.1922x; 1.0237x over previous
//
#include <hip/hip_runtime.h>
#include <math.h>

#define NEXP 64
#define TOPK 8
#define TILE 128          // tokens per block; 2 waves, wave-private LDS halves
#define HPITCH 33         // 32 experts + 1 pad: conflict-free stage, 2-way sweep

typedef float v4 __attribute__((ext_vector_type(4)));

__global__ __launch_bounds__(TILE, 4) void router_kernel(
    const float* __restrict__ logits,
    float* __restrict__ out_logits,
    float* __restrict__ out_rw,
    float* __restrict__ out_tw,
    float* __restrict__ out_ti,
    float* __restrict__ out_hist,
    int nTiles)
{
    // per-wave half-tile: 64 tokens x 32 experts, pitch 33 -> 8448 B per wave
    __shared__ float halfbuf[2][64 * HPITCH];
    __shared__ float shist[NEXP];

    const int tid = threadIdx.x;
    const int w   = tid >> 6;
    const int l   = tid & 63;
    const int q   = l & 15;               // expert-quad this lane's regs hold
    if (tid < NEXP) shist[tid] = 0.0f;
    __syncthreads();                      // shist visible to both waves

    float* __restrict__ hb = &halfbuf[w][0];

    #pragma unroll
    for (int t = 0; t < 2; ++t) {
        const int tb = blockIdx.x + t * gridDim.x;
        if (tb >= nTiles) break;
        const long waveBase = (long)tb * TILE + (w << 6);   // this wave's 64 tokens

        // ---- coalesced NT load of wave's 64x64 region into registers ----
        const v4* g = (const v4*)logits + waveBase * (NEXP / 4);
        v4 row[16];
        #pragma unroll
        for (int k = 0; k < 16; ++k)
            row[k] = __builtin_nontemporal_load(&g[l + (k << 6)]);

        // ---- passthrough from registers (coalesced plain stores) ----
        v4* gp = (v4*)out_logits + waveBase * (NEXP / 4);
        #pragma unroll
        for (int k = 0; k < 16; ++k)
            gp[l + (k << 6)] = row[k];

        // ---- stage half A (experts 0..31): lanes with q<8 write their 16 v4 ----
        // float addr = r*HPITCH + 4q + u, r=(l>>4)+4k: banks (l>>4)+4q+u+4k mod 32
        // = 32 distinct over active lanes -> conflict-free.
        if (q < 8) {
            #pragma unroll
            for (int k = 0; k < 16; ++k) {
                int r = (l >> 4) + (k << 2);
                float* b = &hb[r * HPITCH + (q << 2)];
                v4 v = row[k];
                b[0] = v.x; b[1] = v.y; b[2] = v.z; b[3] = v.w;
            }
        }

        // ---- sweep experts 0..31: top-8 insert (strict >, low-index ties) + sum(exp)
        const float* __restrict__ myrow = &hb[l * HPITCH];
        float vals[TOPK], ids[TOPK];
        #pragma unroll
        for (int j = 0; j < TOPK; ++j) { vals[j] = -INFINITY; ids[j] = 0.0f; }
        float ssum = 0.0f;

        #pragma unroll 8
        for (int e = 0; e < 32; ++e) {
            float x = myrow[e];
            ssum += __expf(x);
            float fe = (float)e;
            bool c[TOPK];
            #pragma unroll
            for (int j = 0; j < TOPK; ++j) c[j] = x > vals[j];
            #pragma unroll
            for (int j = TOPK - 1; j >= 1; --j) {
                ids[j]  = c[j] ? (c[j - 1] ? ids[j - 1] : fe) : ids[j];
                vals[j] = __builtin_amdgcn_fmed3f(x, vals[j - 1], vals[j]);
            }
            ids[0]  = c[0] ? fe : ids[0];
            vals[0] = fmaxf(vals[0], x);
        }

        // ---- stage half B (experts 32..63) over the same region ----
        // DS pipe is in-order per wave: sweep-A reads precede these writes.
        if (q >= 8) {
            #pragma unroll
            for (int k = 0; k < 16; ++k) {
                int r = (l >> 4) + (k << 2);
                float* b = &hb[r * HPITCH + ((q - 8) << 2)];
                v4 v = row[k];
                b[0] = v.x; b[1] = v.y; b[2] = v.z; b[3] = v.w;
            }
        }

        // ---- sweep experts 32..63 (state carried; identical op order) ----
        #pragma unroll 8
        for (int e = 32; e < NEXP; ++e) {
            float x = myrow[e - 32];
            ssum += __expf(x);
            float fe = (float)e;
            bool c[TOPK];
            #pragma unroll
            for (int j = 0; j < TOPK; ++j) c[j] = x > vals[j];
            #pragma unroll
            for (int j = TOPK - 1; j >= 1; --j) {
                ids[j]  = c[j] ? (c[j - 1] ? ids[j - 1] : fe) : ids[j];
                vals[j] = __builtin_amdgcn_fmed3f(x, vals[j - 1], vals[j]);
            }
            ids[0]  = c[0] ? fe : ids[0];
            vals[0] = fmaxf(vals[0], x);
        }
        const float sinv = 1.0f / ssum;

        // ---- top-k weights from registers (softmax denominator cancels) ----
        float ew[TOPK];
        float tsum = 0.0f;
        #pragma unroll
        for (int j = 0; j < TOPK; ++j) { ew[j] = __expf(vals[j]); tsum += ew[j]; }
        const float tinv = 1.0f / tsum;

        const long tok = waveBase + l;
        v4* twp = (v4*)out_tw + tok * 2;
        v4* tip = (v4*)out_ti + tok * 2;
        v4 w0 = { ew[0] * tinv, ew[1] * tinv, ew[2] * tinv, ew[3] * tinv };
        v4 w1 = { ew[4] * tinv, ew[5] * tinv, ew[6] * tinv, ew[7] * tinv };
        v4 i0 = { ids[0], ids[1], ids[2], ids[3] };
        v4 i1 = { ids[4], ids[5], ids[6], ids[7] };
        twp[0] = w0;
        twp[1] = w1;
        tip[0] = i0;
        tip[1] = i1;

        // ---- histogram into block-local LDS ----
        #pragma unroll
        for (int j = 0; j < TOPK; ++j)
            atomicAdd(&shist[(int)ids[j]], 1.0f);

        // ---- rw from register row: exp(x) * shfl(sinv), coalesced stores ----
        v4* grw = (v4*)out_rw + waveBase * (NEXP / 4);
        #pragma unroll
        for (int k = 0; k < 16; ++k) {
            float si = __shfl(sinv, (l >> 4) + (k << 2));   // wave-local owner lane
            v4 x = row[k];
            v4 o;
            o.x = __expf(x.x) * si;
            o.y = __expf(x.y) * si;
            o.z = __expf(x.z) * si;
            o.w = __expf(x.w) * si;
            grw[l + (k << 6)] = o;
        }
    }

    // ---- flush histogram: one 64-lane global atomic per block ----
    __syncthreads();
    if (tid < NEXP) atomicAdd(&out_hist[tid], shist[tid]);
}

extern "C" void kernel_launch(void* const* d_in, const int* in_sizes, int n_in,
                              void* d_out, int out_size, void* d_ws, size_t ws_size,
                              hipStream_t stream) {
    const float* logits = (const float*)d_in[0];
    const long T = (long)in_sizes[0] / NEXP;

    float* out      = (float*)d_out;
    float* o_logits = out;
    float* o_rw     = out + T * NEXP;
    float* o_tw     = out + 2 * T * NEXP;
    float* o_ti     = o_tw + T * TOPK;
    float* o_hist   = o_ti + T * TOPK;

    (void)hipMemsetAsync(o_hist, 0, NEXP * sizeof(float), stream);

    const int nTiles = (int)(T / TILE);        // 4096
    const int grid   = (nTiles + 1) / 2;       // 2048 blocks x 2 tiles
    router_kernel<<<grid, TILE, 0, stream>>>(logits, o_logits, o_rw, o_tw, o_ti,
                                             o_hist, nTiles);
}